// Round 9
// baseline (354.884 us; speedup 1.0000x reference)
//
#include <hip/hip_runtime.h>
#include <hip/hip_fp16.h>

// RGCN: out = hetero(relu(hetero(x, W1,b1)), W2,b2)
// Layer 1 (IN=HID=128): fused 3-relation gather of x16 -> Z(Nx384), then
//   H16 = fp16(relu(bsum1 + Z @ W1)) via MFMA (W in B-frag layout).
// Layer 2 (OUT=64 < HID): GEMM-FIRST — Y2_r = H16 @ W2_r (fp16, 3x Nx64),
//   then gather_out sums coeff*Y2_r rows + bias -> fp32 out.
// Gather L1 (R17): QUARTER-WAVE per edge (16 lanes x uint4 = 256B row),
//   one uniform predicated 24-edge window, 2-step shfl reduce. ~72us.
// R20: (a) gather_out reshaped to EIGHTH-WAVE per edge (8 lanes x uint4 =
//   128B row -> 8 edges per load instr; window 32 = 4 loads in flight;
//   3-step reduce) — same lever that won R16->R17 on the 256B gather.
//   (b) NT isolated: esrc loads + Z16 stores nontemporal so the 48MB of
//   streams stop evicting x16/Y2 random-read hot sets in L2.
// R18 lesson: zero global atomics (ebs+pbs path). R19: CHUNK 2048 / BK 512.

constexpr int N   = 50000;
constexpr int R   = 3;
constexpr int IN  = 128;
constexpr int HID = 128;
constexpr int OUT = 64;
constexpr int M   = R * N;
constexpr int BK  = 512;
constexpr int NBKT = (M + BK - 1) / BK;    // 293
constexpr int CHUNK = 2048;
constexpr int KB  = 24;                    // 384/16 k-blocks for MFMA
constexpr int CVT_N4 = N * IN / 4;         // 1.6M float4 groups
constexpr int WPK   = 6 * KB * 64;         // 9216 weight frags
constexpr int WPK_B = (WPK + 255) / 256;   // 36 blocks

typedef _Float16 half8 __attribute__((ext_vector_type(8)));
typedef float floatx16 __attribute__((ext_vector_type(16)));
typedef unsigned uintx4 __attribute__((ext_vector_type(4)));

// ---- prep: bsum (block 0) + wpack (blocks 1..36) + x fp32->fp16 (rest) ----
__global__ void prep_kernel(const float* __restrict__ x,
                            const float* __restrict__ W1, const float* __restrict__ W2,
                            const float* __restrict__ b1, const float* __restrict__ b2,
                            uint2* __restrict__ x16,
                            __half* __restrict__ F1, __half* __restrict__ F2,
                            float* __restrict__ bsum1, float* __restrict__ bsum2) {
    int b = blockIdx.x;
    if (b == 0) {
        int t = threadIdx.x;
        if (t < HID) bsum1[t] = b1[t] + b1[HID + t] + b1[2 * HID + t];
        if (t < OUT) bsum2[t] = b2[t] + b2[OUT + t] + b2[2 * OUT + t];
        return;
    }
    if (b <= WPK_B) {
        int idx = (b - 1) * 256 + threadIdx.x;
        if (idx < 4 * KB * 64) {
            int nt = idx / (KB * 64), rem = idx % (KB * 64);
            int kb = rem / 64, lane = rem % 64;
            int c = nt * 32 + (lane & 31);
            int k0 = kb * 16 + (lane >> 5) * 8;
            __half h[8];
#pragma unroll
            for (int j = 0; j < 8; j++) h[j] = __float2half_rn(W1[(k0 + j) * 128 + c]);
            *(uint4*)(F1 + (size_t)idx * 8) = *(uint4*)h;
        } else if (idx < 6 * KB * 64) {
            int i2 = idx - 4 * KB * 64;
            int nt = i2 / (KB * 64), rem = i2 % (KB * 64);
            int kb = rem / 64, lane = rem % 64;
            int c = nt * 32 + (lane & 31);
            int k0 = kb * 16 + (lane >> 5) * 8;
            __half h[8];
#pragma unroll
            for (int j = 0; j < 8; j++) h[j] = __float2half_rn(W2[(k0 + j) * 64 + c]);
            *(uint4*)(F2 + (size_t)i2 * 8) = *(uint4*)h;
        }
        return;
    }
    int i = (b - 1 - WPK_B) * 256 + threadIdx.x;
    if (i >= CVT_N4) return;
    float4 v = ((const float4*)x)[i];
    __half2 a = __floats2half2_rn(v.x, v.y);
    __half2 c = __floats2half2_rn(v.z, v.w);
    uint2 o;
    o.x = *(unsigned*)&a;
    o.y = *(unsigned*)&c;
    x16[i] = o;
}

// ---- P1: coarse bucket histograms per edge-chunk (dst + src sides) ----
__global__ __launch_bounds__(256) void p1_kernel(const int* __restrict__ src,
                                                 const int* __restrict__ dst,
                                                 int E, int RE, int nb,
                                                 int* __restrict__ bh) {
    __shared__ int hd[NBKT], hs[NBKT];
    for (int i = threadIdx.x; i < NBKT; i += 256) { hd[i] = 0; hs[i] = 0; }
    __syncthreads();
    int beg = blockIdx.x * CHUNK, end = min(RE, beg + CHUNK);
    for (int g = beg + (int)threadIdx.x; g < end; g += 256) {
        int rb = ((g >= E) + (g >= 2 * E)) * N;
        atomicAdd(&hd[(rb + dst[g]) >> 9], 1);
        atomicAdd(&hs[(rb + src[g]) >> 9], 1);
    }
    __syncthreads();
    for (int i = threadIdx.x; i < NBKT; i += 256) {
        bh[i * nb + blockIdx.x] = hd[i];
        bh[(NBKT + i) * nb + blockIdx.x] = hs[i];
    }
}

// ---- 2-stage exclusive scan (stage-3 folded into consumers) ----
__global__ void scan1_kernel(const int* __restrict__ in, int* __restrict__ out,
                             int* __restrict__ partials, int L) {
    __shared__ int lds[1024];
    int t = threadIdx.x;
    int idx = blockIdx.x * 1024 + t;
    int v = (idx < L) ? in[idx] : 0;
    lds[t] = v;
    __syncthreads();
    for (int off = 1; off < 1024; off <<= 1) {
        int u = (t >= off) ? lds[t - off] : 0;
        __syncthreads();
        lds[t] += u;
        __syncthreads();
    }
    if (idx < L) out[idx] = lds[t] - v;
    if (t == 1023) partials[blockIdx.x] = lds[1023];
}

// 1024-thread scan over up to 1024 partials (nb1 <= 1024)
__global__ void scan2_kernel(int* __restrict__ partials, int nb1) {
    __shared__ int lds[1024];
    int t = threadIdx.x;
    int v = (t < nb1) ? partials[t] : 0;
    lds[t] = v;
    __syncthreads();
    for (int off = 1; off < 1024; off <<= 1) {
        int u = (t >= off) ? lds[t - off] : 0;
        __syncthreads();
        lds[t] += u;
        __syncthreads();
    }
    if (t < nb1) partials[t] = lds[t] - v;
}

// ---- P3: scatter edges into bucket-sorted buffers via LDS cursors ----
// ebd[pos] = (src<<9)|(dkey&511); ebs[pos] = skey&511 (ushort)
__global__ __launch_bounds__(256) void p3_kernel(const int* __restrict__ src,
                                                 const int* __restrict__ dst,
                                                 int E, int RE, int nb,
                                                 const int* __restrict__ scanv,
                                                 const int* __restrict__ partials,
                                                 int* __restrict__ ebd,
                                                 unsigned short* __restrict__ ebs) {
    __shared__ int cd[NBKT], cs[NBKT];
    for (int i = threadIdx.x; i < NBKT; i += 256) {
        int id = i * nb + blockIdx.x;
        int is = (NBKT + i) * nb + blockIdx.x;
        cd[i] = scanv[id] + partials[id >> 10];
        cs[i] = scanv[is] + partials[is >> 10] - RE;
    }
    __syncthreads();
    int beg = blockIdx.x * CHUNK, end = min(RE, beg + CHUNK);
    for (int g = beg + (int)threadIdx.x; g < end; g += 256) {
        int rb = ((g >= E) + (g >= 2 * E)) * N;
        int s  = src[g];
        int kd = rb + dst[g];
        int pd = atomicAdd(&cd[kd >> 9], 1);
        ebd[pd] = (s << 9) | (kd & 511);
        int ks = rb + s;
        int ps = atomicAdd(&cs[ks >> 9], 1);
        ebs[ps] = (unsigned short)(ks & 511);
    }
}

// ---- PB-S: per s-bucket exact histogram -> rs_out ----
__global__ __launch_bounds__(512) void pbs_kernel(const int* __restrict__ scanv,
                                                  const int* __restrict__ partials,
                                                  int nb, int RE,
                                                  const unsigned short* __restrict__ ebs,
                                                  float* __restrict__ rs_out) {
    __shared__ int cnt[BK];
    int t = threadIdx.x;
    int k = blockIdx.x;
    int i0 = (NBKT + k) * nb;
    int segbeg = scanv[i0] + partials[i0 >> 10] - RE;
    int segend;
    if (k == NBKT - 1) segend = RE;
    else {
        int i1 = i0 + nb;
        segend = scanv[i1] + partials[i1 >> 10] - RE;
    }
    cnt[t] = 0;
    __syncthreads();
    for (int e = segbeg + t; e < segend; e += BK)
        atomicAdd(&cnt[(int)ebs[e]], 1);
    __syncthreads();
    int slot = k * BK + t;
    if (slot < M) rs_out[slot] = rsqrtf((float)(cnt[t] + 1));
}

// ---- PB-D: per d-bucket histogram -> row_ptr/rs_in, scatter coeff-packed esrc ----
__global__ __launch_bounds__(512) void pbd_kernel(const int* __restrict__ scanv,
                                                  const int* __restrict__ partials,
                                                  int nb, int RE,
                                                  const int* __restrict__ ebd,
                                                  const float* __restrict__ rs_out,
                                                  int* __restrict__ row_ptr,
                                                  float* __restrict__ rs_in,
                                                  unsigned int* __restrict__ esrc) {
    __shared__ int cnt[BK];
    __shared__ int cur[BK];
    int t = threadIdx.x;
    int k = blockIdx.x;
    int i0 = k * nb;
    int segbeg = scanv[i0] + partials[i0 >> 10];
    int segend;
    if (k == NBKT - 1) segend = RE;
    else {
        int i1 = (k + 1) * nb;
        segend = scanv[i1] + partials[i1 >> 10];
    }
    cnt[t] = 0;
    __syncthreads();
    for (int e = segbeg + t; e < segend; e += BK)
        atomicAdd(&cnt[ebd[e] & 511], 1);
    __syncthreads();
    int slot = k * BK + t;
    int c = cnt[t];
    cur[t] = c;
    __syncthreads();
    for (int off = 1; off < BK; off <<= 1) {
        int u = (t >= off) ? cur[t - off] : 0;
        __syncthreads();
        cur[t] += u;
        __syncthreads();
    }
    int excl = cur[t] - c;
    if (slot < M) {
        row_ptr[slot] = segbeg + excl;
        rs_in[slot] = rsqrtf((float)(c + 1));   // +1 self-loop
    }
    if (k == NBKT - 1 && t == 0) row_ptr[M] = RE;
    __syncthreads();
    cur[t] = segbeg + excl;
    __syncthreads();
    for (int e = segbeg + t; e < segend; e += BK) {
        int v = ebd[e];
        int key = k * BK + (v & 511);
        int r = (key >= 2 * N) + (key >= N);
        unsigned s = (unsigned)(v >> 9);
        int pos = atomicAdd(&cur[v & 511], 1);
        __half h = __float2half_rn(rs_out[r * N + s]);
        esrc[pos] = s | ((unsigned)__half_as_ushort(h) << 16);
    }
}

// ---- layer-1 gather (R17 shape + R20 NT): one wave per node; QUARTER-WAVE
// (16 lanes x uint4 = 256B row) per edge -> 4 edges/instr; one uniform
// predicated 24-edge window; 2-step shfl_xor(16,32) reduce. NT esrc loads
// + NT Z16 stores keep streams out of the x16 L2 hot set. ----
__global__ __launch_bounds__(256) void gather_kernel(const __half* __restrict__ Xh,
                                                     const float* __restrict__ rs_in,
                                                     const float* __restrict__ rs_out,
                                                     const int* __restrict__ row_ptr,
                                                     const unsigned int* __restrict__ esrc,
                                                     __half* __restrict__ Z16) {
    int n = blockIdx.x * 4 + (threadIdx.x >> 6);
    if (n >= N) return;
    int lane = threadIdx.x & 63;
    int g = lane >> 4;                       // edge sub-slot 0..3
    int cl = lane & 15;                      // 8 cols: c = cl*8
    const __half* xrow = Xh + (long)n * 128 + cl * 8;
    uint4 xn = *(const uint4*)xrow;
#pragma unroll
    for (int r = 0; r < R; r++) {
        int key = r * N + n;
        int beg = row_ptr[key], end = row_ptr[key + 1];
        __half2 a0 = __float2half2_rn(0.f), a1 = a0, a2 = a0, a3 = a0;
        for (int e = beg; e < end; e += 24) {
            unsigned u[6];
#pragma unroll
            for (int j = 0; j < 6; j++) {
                int idx = e + 4 * j + g;
                u[j] = (idx < end) ? __builtin_nontemporal_load(esrc + idx) : 0u;
            }
            uint4 y[6];
#pragma unroll
            for (int j = 0; j < 6; j++)
                y[j] = *(const uint4*)(Xh + (long)(u[j] & 0xffffu) * 128 + cl * 8);
#pragma unroll
            for (int j = 0; j < 6; j++) {
                __half2 cj = __half2half2(__ushort_as_half((unsigned short)(u[j] >> 16)));
                a0 = __hfma2(*(__half2*)&y[j].x, cj, a0);
                a1 = __hfma2(*(__half2*)&y[j].y, cj, a1);
                a2 = __hfma2(*(__half2*)&y[j].z, cj, a2);
                a3 = __hfma2(*(__half2*)&y[j].w, cj, a3);
            }
        }
        // reduce over the 4 edge sub-slots (lanes l, l^16, l^32, l^48)
#pragma unroll
        for (int off = 16; off < 64; off <<= 1) {
            unsigned w0 = *(unsigned*)&a0, w1 = *(unsigned*)&a1;
            unsigned w2 = *(unsigned*)&a2, w3 = *(unsigned*)&a3;
            unsigned v0 = (unsigned)__shfl_xor((int)w0, off, 64);
            unsigned v1 = (unsigned)__shfl_xor((int)w1, off, 64);
            unsigned v2 = (unsigned)__shfl_xor((int)w2, off, 64);
            unsigned v3 = (unsigned)__shfl_xor((int)w3, off, 64);
            a0 = __hadd2(a0, *(__half2*)&v0);
            a1 = __hadd2(a1, *(__half2*)&v1);
            a2 = __hadd2(a2, *(__half2*)&v2);
            a3 = __hadd2(a3, *(__half2*)&v3);
        }
        __half2 cs = __float2half2_rn(rs_out[key]);
        a0 = __hfma2(*(__half2*)&xn.x, cs, a0);
        a1 = __hfma2(*(__half2*)&xn.y, cs, a1);
        a2 = __hfma2(*(__half2*)&xn.z, cs, a2);
        a3 = __hfma2(*(__half2*)&xn.w, cs, a3);
        __half2 ri = __float2half2_rn(rs_in[key]);
        a0 = __hmul2(a0, ri);
        a1 = __hmul2(a1, ri);
        a2 = __hmul2(a2, ri);
        a3 = __hmul2(a3, ri);
        if (g == 0) {
            uintx4 o;
            o.x = *(unsigned*)&a0;
            o.y = *(unsigned*)&a1;
            o.z = *(unsigned*)&a2;
            o.w = *(unsigned*)&a3;
            __builtin_nontemporal_store(
                o, (uintx4*)(Z16 + (long)n * 384 + r * 128 + cl * 8));
        }
    }
}

// ---- layer-1 MFMA GEMM: H16 = fp16(relu(bias + Z16[N,384] @ W1)); A-frags
// direct from Z16 rows, B-frags from F1. 32x32x16 f16.
// C/D map: col=lane&31, row=(reg&3)+8*(reg>>2)+4*(lane>>5)  [m74/m101 verified]
__global__ __launch_bounds__(256) void mfma_gemm1_kernel(const __half* __restrict__ Z16,
                                                         const __half* __restrict__ F,
                                                         const float* __restrict__ bias,
                                                         __half* __restrict__ H16) {
    int wave = threadIdx.x >> 6, lane = threadIdx.x & 63;
    int m0 = blockIdx.x * 128 + wave * 32;
    int mr = min(m0 + (lane & 31), N - 1);
    const half8* A = (const half8*)(Z16 + (long)mr * 384 + (lane >> 5) * 8);
    const half8* B = (const half8*)F;
    floatx16 acc[4];
#pragma unroll
    for (int i = 0; i < 4; i++)
#pragma unroll
        for (int j = 0; j < 16; j++) acc[i][j] = 0.f;

    half8 a = A[0];
    for (int kb = 0; kb < KB; kb++) {
        half8 an = (kb < KB - 1) ? A[(kb + 1) * 2] : a;
#pragma unroll
        for (int nt = 0; nt < 4; nt++) {
            half8 b = B[(nt * KB + kb) * 64 + lane];
            acc[nt] = __builtin_amdgcn_mfma_f32_32x32x16_f16(a, b, acc[nt], 0, 0, 0);
        }
        a = an;
    }
    float bv[4];
#pragma unroll
    for (int nt = 0; nt < 4; nt++) bv[nt] = bias[nt * 32 + (lane & 31)];
    int rbase = m0 + 4 * (lane >> 5);
    int col0 = lane & 31;
#pragma unroll
    for (int nt = 0; nt < 4; nt++) {
#pragma unroll
        for (int reg = 0; reg < 16; reg++) {
            int row = rbase + (reg & 3) + 8 * (reg >> 2);
            if (row < N) {
                float v = fmaxf(acc[nt][reg] + bv[nt], 0.f);
                H16[(long)row * 128 + nt * 32 + col0] = __float2half_rn(v);
            }
        }
    }
}

// ---- layer-2 GEMM-first: Y2[r][N][64] = H16[N,128] @ W2_r (fp16 out, no bias).
// F2 kb-layout: relation r's K-chunk is kb = r*8 + kbr. blockIdx.y = r. ----
__global__ __launch_bounds__(256) void mfma_gemmY_kernel(const __half* __restrict__ H16,
                                                         const __half* __restrict__ F,
                                                         __half* __restrict__ Y2) {
    int wave = threadIdx.x >> 6, lane = threadIdx.x & 63;
    int r = blockIdx.y;
    int m0 = blockIdx.x * 128 + wave * 32;
    int mr = min(m0 + (lane & 31), N - 1);
    const half8* A = (const half8*)(H16 + (long)mr * 128 + (lane >> 5) * 8);
    const half8* B = (const half8*)F;
    floatx16 acc[2];
#pragma unroll
    for (int i = 0; i < 2; i++)
#pragma unroll
        for (int j = 0; j < 16; j++) acc[i][j] = 0.f;

#pragma unroll
    for (int kbr = 0; kbr < 8; kbr++) {
        half8 a = A[kbr * 2];
#pragma unroll
        for (int nt = 0; nt < 2; nt++) {
            half8 b = B[(nt * KB + r * 8 + kbr) * 64 + lane];
            acc[nt] = __builtin_amdgcn_mfma_f32_32x32x16_f16(a, b, acc[nt], 0, 0, 0);
        }
    }
    int rbase = m0 + 4 * (lane >> 5);
    int col0 = lane & 31;
    __half* Yr = Y2 + (long)r * N * 64;
#pragma unroll
    for (int nt = 0; nt < 2; nt++) {
#pragma unroll
        for (int reg = 0; reg < 16; reg++) {
            int row = rbase + (reg & 3) + 8 * (reg >> 2);
            if (row < N)
                Yr[(long)row * 64 + nt * 32 + col0] = __float2half_rn(acc[nt][reg]);
        }
    }
}

// ---- layer-2 gather (R20): EIGHTH-WAVE per edge — 8 lanes x uint4 = 128B
// row -> 8 edges per load instr; one uniform predicated 32-edge window
// (4 loads in flight/lane); 3-step shfl_xor(8,16,32) reduce; NT esrc loads.
// Lanes 0-7 store 2x float4 (256B out row). ----
__global__ __launch_bounds__(256) void gather_out_kernel(const __half* __restrict__ Y2,
                                                         const float* __restrict__ rs_in,
                                                         const float* __restrict__ rs_out,
                                                         const int* __restrict__ row_ptr,
                                                         const unsigned int* __restrict__ esrc,
                                                         const float* __restrict__ bias,
                                                         float* __restrict__ outp) {
    int n = blockIdx.x * 4 + (threadIdx.x >> 6);
    if (n >= N) return;
    int lane = threadIdx.x & 63;
    int g = lane >> 3;                      // edge sub-slot 0..7
    int cl = lane & 7;                      // 8 cols: c = cl*8
    float4 tlo = ((const float4*)bias)[cl * 2];
    float4 thi = ((const float4*)bias)[cl * 2 + 1];
#pragma unroll
    for (int r = 0; r < R; r++) {
        int key = r * N + n;
        const __half* Yr = Y2 + (long)r * N * 64;
        __half2 a0 = __float2half2_rn(0.f), a1 = a0, a2 = a0, a3 = a0;
        int beg = row_ptr[key], end = row_ptr[key + 1];
        for (int e = beg; e < end; e += 32) {
            unsigned u[4];
#pragma unroll
            for (int j = 0; j < 4; j++) {
                int idx = e + 8 * j + g;
                u[j] = (idx < end) ? __builtin_nontemporal_load(esrc + idx) : 0u;
            }
            uint4 y[4];
#pragma unroll
            for (int j = 0; j < 4; j++)
                y[j] = *(const uint4*)(Yr + (long)(u[j] & 0xffffu) * 64 + cl * 8);
#pragma unroll
            for (int j = 0; j < 4; j++) {
                __half2 cj = __half2half2(__ushort_as_half((unsigned short)(u[j] >> 16)));
                a0 = __hfma2(*(__half2*)&y[j].x, cj, a0);
                a1 = __hfma2(*(__half2*)&y[j].y, cj, a1);
                a2 = __hfma2(*(__half2*)&y[j].z, cj, a2);
                a3 = __hfma2(*(__half2*)&y[j].w, cj, a3);
            }
        }
        // reduce over the 8 edge sub-slots
#pragma unroll
        for (int off = 8; off < 64; off <<= 1) {
            unsigned w0 = *(unsigned*)&a0, w1 = *(unsigned*)&a1;
            unsigned w2 = *(unsigned*)&a2, w3 = *(unsigned*)&a3;
            unsigned v0 = (unsigned)__shfl_xor((int)w0, off, 64);
            unsigned v1 = (unsigned)__shfl_xor((int)w1, off, 64);
            unsigned v2 = (unsigned)__shfl_xor((int)w2, off, 64);
            unsigned v3 = (unsigned)__shfl_xor((int)w3, off, 64);
            a0 = __hadd2(a0, *(__half2*)&v0);
            a1 = __hadd2(a1, *(__half2*)&v1);
            a2 = __hadd2(a2, *(__half2*)&v2);
            a3 = __hadd2(a3, *(__half2*)&v3);
        }
        // self-loop
        uint4 ys = *(const uint4*)(Yr + (long)n * 64 + cl * 8);
        __half2 cs = __float2half2_rn(rs_out[key]);
        a0 = __hfma2(*(__half2*)&ys.x, cs, a0);
        a1 = __hfma2(*(__half2*)&ys.y, cs, a1);
        a2 = __hfma2(*(__half2*)&ys.z, cs, a2);
        a3 = __hfma2(*(__half2*)&ys.w, cs, a3);
        float2 f0 = __half22float2(a0);
        float2 f1 = __half22float2(a1);
        float2 f2 = __half22float2(a2);
        float2 f3 = __half22float2(a3);
        float ri = rs_in[key];
        tlo.x += ri * f0.x;
        tlo.y += ri * f0.y;
        tlo.z += ri * f1.x;
        tlo.w += ri * f1.y;
        thi.x += ri * f2.x;
        thi.y += ri * f2.y;
        thi.z += ri * f3.x;
        thi.w += ri * f3.y;
    }
    if (g == 0) {
        *(float4*)(outp + (long)n * 64 + cl * 8) = tlo;
        *(float4*)(outp + (long)n * 64 + cl * 8 + 4) = thi;
    }
}

extern "C" void kernel_launch(void* const* d_in, const int* in_sizes, int n_in,
                              void* d_out, int out_size, void* d_ws, size_t ws_size,
                              hipStream_t stream) {
    const float* x  = (const float*)d_in[0];
    const int*  src = (const int*)d_in[1];
    const int*  dst = (const int*)d_in[2];
    const float* W1 = (const float*)d_in[3];   // [384][128]
    const float* b1 = (const float*)d_in[4];
    const float* W2 = (const float*)d_in[5];   // [384][64]
    const float* b2 = (const float*)d_in[6];
    float* out = (float*)d_out;
    const int E  = in_sizes[1] / R;
    const int RE = in_sizes[1];
    const int nb = (RE + CHUNK - 1) / CHUNK;      // 1172 edge chunks
    const int L  = 2 * NBKT * nb;                 // ~687k
    const int nb1 = (L + 1023) / 1024;            // ~671 (<=1024)

    char* ws = (char*)d_ws;
    size_t off = 0;
    auto alloc = [&](size_t bytes) -> void* {
        void* p = ws + off;
        off += (bytes + 255) & ~(size_t)255;
        return p;
    };
    float* bsum1    = (float*)alloc(HID * 4);
    float* bsum2    = (float*)alloc(OUT * 4);
    float* rs_in    = (float*)alloc((size_t)M * 4);
    float* rs_out   = (float*)alloc((size_t)M * 4);
    int*   row_ptr  = (int*)alloc((size_t)(M + 1) * 4);
    int*   bh       = (int*)alloc((size_t)L * 4);
    int*   scanv    = (int*)alloc((size_t)L * 4);
    int*   partials = (int*)alloc((size_t)nb1 * 4);
    unsigned* esrc  = (unsigned*)alloc((size_t)RE * 4);
    __half* F1      = (__half*)alloc((size_t)4 * KB * 64 * 8 * 2);
    __half* F2      = (__half*)alloc((size_t)2 * KB * 64 * 8 * 2);
    // region A: ebd(9.6MB)+ebs(4.8MB) during build; Z16 (38.4MB) for layer 1;
    // Y2 (19.2MB) for layer 2 (Z16 dead after gemm1).
    char*  regA     = (char*)alloc((size_t)N * 384 * 2);
    int*   ebd      = (int*)regA;
    unsigned short* ebs = (unsigned short*)(regA + (size_t)RE * 4);
    __half* Z16     = (__half*)regA;
    __half* Y2      = (__half*)regA;
    __half* x16     = (__half*)alloc((size_t)N * IN * 2);
    __half* H16     = (__half*)alloc((size_t)N * HID * 2);

    prep_kernel<<<1 + WPK_B + (CVT_N4 + 255) / 256, 256, 0, stream>>>(
        x, W1, W2, b1, b2, (uint2*)x16, F1, F2, bsum1, bsum2);
    p1_kernel<<<nb, 256, 0, stream>>>(src, dst, E, RE, nb, bh);
    scan1_kernel<<<nb1, 1024, 0, stream>>>(bh, scanv, partials, L);
    scan2_kernel<<<1, 1024, 0, stream>>>(partials, nb1);
    p3_kernel<<<nb, 256, 0, stream>>>(src, dst, E, RE, nb, scanv, partials, ebd, ebs);
    pbs_kernel<<<NBKT, BK, 0, stream>>>(scanv, partials, nb, RE, ebs, rs_out);
    pbd_kernel<<<NBKT, BK, 0, stream>>>(scanv, partials, nb, RE, ebd, rs_out,
                                        row_ptr, rs_in, esrc);

    const int ab  = (N + 3) / 4;              // 12500 gather blocks
    const int ggb = (N + 127) / 128;          // 391 gemm blocks

    // layer 1: Z = gather(x16); H16 = fp16(relu(bsum1 + Z @ W1))
    gather_kernel<<<ab, 256, 0, stream>>>(x16, rs_in, rs_out, row_ptr, esrc, Z16);
    mfma_gemm1_kernel<<<ggb, 256, 0, stream>>>(Z16, F1, bsum1, H16);
    // layer 2 (GEMM-first): Y2_r = H16 @ W2_r; out = bsum2 + agg(Y2)
    mfma_gemmY_kernel<<<dim3(ggb, R), 256, 0, stream>>>(H16, F2, Y2);
    gather_out_kernel<<<ab, 256, 0, stream>>>(Y2, rs_in, rs_out, row_ptr, esrc,
                                              bsum2, out);
}

// Round 10
// 349.062 us; speedup vs baseline: 1.0167x; 1.0167x over previous
//
#include <hip/hip_runtime.h>
#include <hip/hip_fp16.h>

// RGCN: out = hetero(relu(hetero(x, W1,b1)), W2,b2)
// Layer 1 (IN=HID=128): fused 3-relation gather of x16 -> Z(Nx384).
// R21: MLP FUSED — one kernel does H = relu(bsum1 + Z@W1) into an LDS tile
//   [128][136] (C/D->A-frag transpose; pad 8 halves = aligned b128, ~free
//   write banks), then Y2_r = H @ W2_r for r=0..2 from LDS A-frags.
//   H16 global round-trip (12.8MB write + 38.4MB read) deleted; 1 launch less.
// Layer 2 tail: gather_out sums coeff*Y2_r rows + bias -> fp32 out.
// Gather (R17/R19, kept): QUARTER-WAVE per edge (16 lanes x uint4 = 256B
//   row), one uniform predicated 24-edge window, 2-step shfl reduce. ~72us,
//   L2-request-throughput-bound (R13: full L2 residency didn't help; R20:
//   NT cut FETCH 5MB, time unchanged). R18 lesson: zero global atomics.

constexpr int N   = 50000;
constexpr int R   = 3;
constexpr int IN  = 128;
constexpr int HID = 128;
constexpr int OUT = 64;
constexpr int M   = R * N;
constexpr int BK  = 512;
constexpr int NBKT = (M + BK - 1) / BK;    // 293
constexpr int CHUNK = 2048;
constexpr int KB  = 24;                    // 384/16 k-blocks for MFMA
constexpr int CVT_N4 = N * IN / 4;         // 1.6M float4 groups
constexpr int WPK   = 6 * KB * 64;         // 9216 weight frags
constexpr int WPK_B = (WPK + 255) / 256;   // 36 blocks

typedef _Float16 half8 __attribute__((ext_vector_type(8)));
typedef float floatx16 __attribute__((ext_vector_type(16)));

// ---- prep: bsum (block 0) + wpack (blocks 1..36) + x fp32->fp16 (rest) ----
__global__ void prep_kernel(const float* __restrict__ x,
                            const float* __restrict__ W1, const float* __restrict__ W2,
                            const float* __restrict__ b1, const float* __restrict__ b2,
                            uint2* __restrict__ x16,
                            __half* __restrict__ F1, __half* __restrict__ F2,
                            float* __restrict__ bsum1, float* __restrict__ bsum2) {
    int b = blockIdx.x;
    if (b == 0) {
        int t = threadIdx.x;
        if (t < HID) bsum1[t] = b1[t] + b1[HID + t] + b1[2 * HID + t];
        if (t < OUT) bsum2[t] = b2[t] + b2[OUT + t] + b2[2 * OUT + t];
        return;
    }
    if (b <= WPK_B) {
        int idx = (b - 1) * 256 + threadIdx.x;
        if (idx < 4 * KB * 64) {
            int nt = idx / (KB * 64), rem = idx % (KB * 64);
            int kb = rem / 64, lane = rem % 64;
            int c = nt * 32 + (lane & 31);
            int k0 = kb * 16 + (lane >> 5) * 8;
            __half h[8];
#pragma unroll
            for (int j = 0; j < 8; j++) h[j] = __float2half_rn(W1[(k0 + j) * 128 + c]);
            *(uint4*)(F1 + (size_t)idx * 8) = *(uint4*)h;
        } else if (idx < 6 * KB * 64) {
            int i2 = idx - 4 * KB * 64;
            int nt = i2 / (KB * 64), rem = i2 % (KB * 64);
            int kb = rem / 64, lane = rem % 64;
            int c = nt * 32 + (lane & 31);
            int k0 = kb * 16 + (lane >> 5) * 8;
            __half h[8];
#pragma unroll
            for (int j = 0; j < 8; j++) h[j] = __float2half_rn(W2[(k0 + j) * 64 + c]);
            *(uint4*)(F2 + (size_t)i2 * 8) = *(uint4*)h;
        }
        return;
    }
    int i = (b - 1 - WPK_B) * 256 + threadIdx.x;
    if (i >= CVT_N4) return;
    float4 v = ((const float4*)x)[i];
    __half2 a = __floats2half2_rn(v.x, v.y);
    __half2 c = __floats2half2_rn(v.z, v.w);
    uint2 o;
    o.x = *(unsigned*)&a;
    o.y = *(unsigned*)&c;
    x16[i] = o;
}

// ---- P1: coarse bucket histograms per edge-chunk (dst + src sides) ----
__global__ __launch_bounds__(256) void p1_kernel(const int* __restrict__ src,
                                                 const int* __restrict__ dst,
                                                 int E, int RE, int nb,
                                                 int* __restrict__ bh) {
    __shared__ int hd[NBKT], hs[NBKT];
    for (int i = threadIdx.x; i < NBKT; i += 256) { hd[i] = 0; hs[i] = 0; }
    __syncthreads();
    int beg = blockIdx.x * CHUNK, end = min(RE, beg + CHUNK);
    for (int g = beg + (int)threadIdx.x; g < end; g += 256) {
        int rb = ((g >= E) + (g >= 2 * E)) * N;
        atomicAdd(&hd[(rb + dst[g]) >> 9], 1);
        atomicAdd(&hs[(rb + src[g]) >> 9], 1);
    }
    __syncthreads();
    for (int i = threadIdx.x; i < NBKT; i += 256) {
        bh[i * nb + blockIdx.x] = hd[i];
        bh[(NBKT + i) * nb + blockIdx.x] = hs[i];
    }
}

// ---- 2-stage exclusive scan (stage-3 folded into consumers) ----
__global__ void scan1_kernel(const int* __restrict__ in, int* __restrict__ out,
                             int* __restrict__ partials, int L) {
    __shared__ int lds[1024];
    int t = threadIdx.x;
    int idx = blockIdx.x * 1024 + t;
    int v = (idx < L) ? in[idx] : 0;
    lds[t] = v;
    __syncthreads();
    for (int off = 1; off < 1024; off <<= 1) {
        int u = (t >= off) ? lds[t - off] : 0;
        __syncthreads();
        lds[t] += u;
        __syncthreads();
    }
    if (idx < L) out[idx] = lds[t] - v;
    if (t == 1023) partials[blockIdx.x] = lds[1023];
}

// 1024-thread scan over up to 1024 partials (nb1 <= 1024)
__global__ void scan2_kernel(int* __restrict__ partials, int nb1) {
    __shared__ int lds[1024];
    int t = threadIdx.x;
    int v = (t < nb1) ? partials[t] : 0;
    lds[t] = v;
    __syncthreads();
    for (int off = 1; off < 1024; off <<= 1) {
        int u = (t >= off) ? lds[t - off] : 0;
        __syncthreads();
        lds[t] += u;
        __syncthreads();
    }
    if (t < nb1) partials[t] = lds[t] - v;
}

// ---- P3: scatter edges into bucket-sorted buffers via LDS cursors ----
// ebd[pos] = (src<<9)|(dkey&511); ebs[pos] = skey&511 (ushort)
__global__ __launch_bounds__(256) void p3_kernel(const int* __restrict__ src,
                                                 const int* __restrict__ dst,
                                                 int E, int RE, int nb,
                                                 const int* __restrict__ scanv,
                                                 const int* __restrict__ partials,
                                                 int* __restrict__ ebd,
                                                 unsigned short* __restrict__ ebs) {
    __shared__ int cd[NBKT], cs[NBKT];
    for (int i = threadIdx.x; i < NBKT; i += 256) {
        int id = i * nb + blockIdx.x;
        int is = (NBKT + i) * nb + blockIdx.x;
        cd[i] = scanv[id] + partials[id >> 10];
        cs[i] = scanv[is] + partials[is >> 10] - RE;
    }
    __syncthreads();
    int beg = blockIdx.x * CHUNK, end = min(RE, beg + CHUNK);
    for (int g = beg + (int)threadIdx.x; g < end; g += 256) {
        int rb = ((g >= E) + (g >= 2 * E)) * N;
        int s  = src[g];
        int kd = rb + dst[g];
        int pd = atomicAdd(&cd[kd >> 9], 1);
        ebd[pd] = (s << 9) | (kd & 511);
        int ks = rb + s;
        int ps = atomicAdd(&cs[ks >> 9], 1);
        ebs[ps] = (unsigned short)(ks & 511);
    }
}

// ---- PB-S: per s-bucket exact histogram -> rs_out ----
__global__ __launch_bounds__(512) void pbs_kernel(const int* __restrict__ scanv,
                                                  const int* __restrict__ partials,
                                                  int nb, int RE,
                                                  const unsigned short* __restrict__ ebs,
                                                  float* __restrict__ rs_out) {
    __shared__ int cnt[BK];
    int t = threadIdx.x;
    int k = blockIdx.x;
    int i0 = (NBKT + k) * nb;
    int segbeg = scanv[i0] + partials[i0 >> 10] - RE;
    int segend;
    if (k == NBKT - 1) segend = RE;
    else {
        int i1 = i0 + nb;
        segend = scanv[i1] + partials[i1 >> 10] - RE;
    }
    cnt[t] = 0;
    __syncthreads();
    for (int e = segbeg + t; e < segend; e += BK)
        atomicAdd(&cnt[(int)ebs[e]], 1);
    __syncthreads();
    int slot = k * BK + t;
    if (slot < M) rs_out[slot] = rsqrtf((float)(cnt[t] + 1));
}

// ---- PB-D: per d-bucket histogram -> row_ptr/rs_in, scatter coeff-packed esrc ----
__global__ __launch_bounds__(512) void pbd_kernel(const int* __restrict__ scanv,
                                                  const int* __restrict__ partials,
                                                  int nb, int RE,
                                                  const int* __restrict__ ebd,
                                                  const float* __restrict__ rs_out,
                                                  int* __restrict__ row_ptr,
                                                  float* __restrict__ rs_in,
                                                  unsigned int* __restrict__ esrc) {
    __shared__ int cnt[BK];
    __shared__ int cur[BK];
    int t = threadIdx.x;
    int k = blockIdx.x;
    int i0 = k * nb;
    int segbeg = scanv[i0] + partials[i0 >> 10];
    int segend;
    if (k == NBKT - 1) segend = RE;
    else {
        int i1 = (k + 1) * nb;
        segend = scanv[i1] + partials[i1 >> 10];
    }
    cnt[t] = 0;
    __syncthreads();
    for (int e = segbeg + t; e < segend; e += BK)
        atomicAdd(&cnt[ebd[e] & 511], 1);
    __syncthreads();
    int slot = k * BK + t;
    int c = cnt[t];
    cur[t] = c;
    __syncthreads();
    for (int off = 1; off < BK; off <<= 1) {
        int u = (t >= off) ? cur[t - off] : 0;
        __syncthreads();
        cur[t] += u;
        __syncthreads();
    }
    int excl = cur[t] - c;
    if (slot < M) {
        row_ptr[slot] = segbeg + excl;
        rs_in[slot] = rsqrtf((float)(c + 1));   // +1 self-loop
    }
    if (k == NBKT - 1 && t == 0) row_ptr[M] = RE;
    __syncthreads();
    cur[t] = segbeg + excl;
    __syncthreads();
    for (int e = segbeg + t; e < segend; e += BK) {
        int v = ebd[e];
        int key = k * BK + (v & 511);
        int r = (key >= 2 * N) + (key >= N);
        unsigned s = (unsigned)(v >> 9);
        int pos = atomicAdd(&cur[v & 511], 1);
        __half h = __float2half_rn(rs_out[r * N + s]);
        esrc[pos] = s | ((unsigned)__half_as_ushort(h) << 16);
    }
}

// ---- layer-1 gather (R17, unchanged): one wave per node; QUARTER-WAVE
// (16 lanes x uint4 = 256B row) per edge -> 4 edges/instr; one uniform
// predicated 24-edge window (6 loads in flight/lane); pred-out lanes load
// row 0 (L1-hot) with coeff +0; 2-step shfl_xor(16,32) reduce. ----
__global__ __launch_bounds__(256) void gather_kernel(const __half* __restrict__ Xh,
                                                     const float* __restrict__ rs_in,
                                                     const float* __restrict__ rs_out,
                                                     const int* __restrict__ row_ptr,
                                                     const unsigned int* __restrict__ esrc,
                                                     __half* __restrict__ Z16) {
    int n = blockIdx.x * 4 + (threadIdx.x >> 6);
    if (n >= N) return;
    int lane = threadIdx.x & 63;
    int g = lane >> 4;                       // edge sub-slot 0..3
    int cl = lane & 15;                      // 8 cols: c = cl*8
    const __half* xrow = Xh + (long)n * 128 + cl * 8;
    uint4 xn = *(const uint4*)xrow;
#pragma unroll
    for (int r = 0; r < R; r++) {
        int key = r * N + n;
        int beg = row_ptr[key], end = row_ptr[key + 1];
        __half2 a0 = __float2half2_rn(0.f), a1 = a0, a2 = a0, a3 = a0;
        for (int e = beg; e < end; e += 24) {
            unsigned u[6];
#pragma unroll
            for (int j = 0; j < 6; j++) {
                int idx = e + 4 * j + g;
                u[j] = (idx < end) ? esrc[idx] : 0u;   // coeff bits 0 -> adds 0
            }
            uint4 y[6];
#pragma unroll
            for (int j = 0; j < 6; j++)
                y[j] = *(const uint4*)(Xh + (long)(u[j] & 0xffffu) * 128 + cl * 8);
#pragma unroll
            for (int j = 0; j < 6; j++) {
                __half2 cj = __half2half2(__ushort_as_half((unsigned short)(u[j] >> 16)));
                a0 = __hfma2(*(__half2*)&y[j].x, cj, a0);
                a1 = __hfma2(*(__half2*)&y[j].y, cj, a1);
                a2 = __hfma2(*(__half2*)&y[j].z, cj, a2);
                a3 = __hfma2(*(__half2*)&y[j].w, cj, a3);
            }
        }
        // reduce over the 4 edge sub-slots (lanes l, l^16, l^32, l^48)
#pragma unroll
        for (int off = 16; off < 64; off <<= 1) {
            unsigned w0 = *(unsigned*)&a0, w1 = *(unsigned*)&a1;
            unsigned w2 = *(unsigned*)&a2, w3 = *(unsigned*)&a3;
            unsigned v0 = (unsigned)__shfl_xor((int)w0, off, 64);
            unsigned v1 = (unsigned)__shfl_xor((int)w1, off, 64);
            unsigned v2 = (unsigned)__shfl_xor((int)w2, off, 64);
            unsigned v3 = (unsigned)__shfl_xor((int)w3, off, 64);
            a0 = __hadd2(a0, *(__half2*)&v0);
            a1 = __hadd2(a1, *(__half2*)&v1);
            a2 = __hadd2(a2, *(__half2*)&v2);
            a3 = __hadd2(a3, *(__half2*)&v3);
        }
        __half2 cs = __float2half2_rn(rs_out[key]);
        a0 = __hfma2(*(__half2*)&xn.x, cs, a0);
        a1 = __hfma2(*(__half2*)&xn.y, cs, a1);
        a2 = __hfma2(*(__half2*)&xn.z, cs, a2);
        a3 = __hfma2(*(__half2*)&xn.w, cs, a3);
        __half2 ri = __float2half2_rn(rs_in[key]);
        a0 = __hmul2(a0, ri);
        a1 = __hmul2(a1, ri);
        a2 = __hmul2(a2, ri);
        a3 = __hmul2(a3, ri);
        if (g == 0) {
            uint4 o;
            o.x = *(unsigned*)&a0;
            o.y = *(unsigned*)&a1;
            o.z = *(unsigned*)&a2;
            o.w = *(unsigned*)&a3;
            *(uint4*)(Z16 + (long)n * 384 + r * 128 + cl * 8) = o;
        }
    }
}

// ---- R21 fused MLP: H = relu(bsum1 + Z16@W1) staged in LDS, then
// Y2_r = H @ W2_r for r=0..2. 4 waves x 32-row strips; LDS [128][136]
// (pad 8 halves -> 16B-aligned b128 A-frag reads, conflict-light).
// C/D map: col=lane&31, row=(reg&3)+8*(reg>>2)+4*(lane>>5)  [m74/m101]
// A-frag map: row=lane&31, k=(lane>>5)*8+j. Each wave only touches its
// own strip in LDS (pure transpose staging). H16 global eliminated. ----
__global__ __launch_bounds__(256) void mfma_mlp_kernel(const __half* __restrict__ Z16,
                                                       const __half* __restrict__ F1,
                                                       const __half* __restrict__ F2,
                                                       const float* __restrict__ bias,
                                                       __half* __restrict__ Y2) {
    __shared__ __half Hs[128][136];
    int wave = threadIdx.x >> 6, lane = threadIdx.x & 63;
    int m0 = blockIdx.x * 128 + wave * 32;
    int mr = min(m0 + (lane & 31), N - 1);
    const half8* A = (const half8*)(Z16 + (long)mr * 384 + (lane >> 5) * 8);
    const half8* B1 = (const half8*)F1;
    floatx16 acc[4];
#pragma unroll
    for (int i = 0; i < 4; i++)
#pragma unroll
        for (int j = 0; j < 16; j++) acc[i][j] = 0.f;

    half8 a = A[0];
    for (int kb = 0; kb < KB; kb++) {
        half8 an = (kb < KB - 1) ? A[(kb + 1) * 2] : a;
#pragma unroll
        for (int nt = 0; nt < 4; nt++) {
            half8 b = B1[(nt * KB + kb) * 64 + lane];
            acc[nt] = __builtin_amdgcn_mfma_f32_32x32x16_f16(a, b, acc[nt], 0, 0, 0);
        }
        a = an;
    }
    float bv[4];
#pragma unroll
    for (int nt = 0; nt < 4; nt++) bv[nt] = bias[nt * 32 + (lane & 31)];
    int lrbase = wave * 32 + 4 * (lane >> 5);
    int col0 = lane & 31;
#pragma unroll
    for (int nt = 0; nt < 4; nt++) {
#pragma unroll
        for (int reg = 0; reg < 16; reg++) {
            int lrow = lrbase + (reg & 3) + 8 * (reg >> 2);
            Hs[lrow][nt * 32 + col0] =
                __float2half_rn(fmaxf(acc[nt][reg] + bv[nt], 0.f));
        }
    }
    __syncthreads();

    // phase 2: Y2_r = H @ W2_r. A-frags from own strip in LDS.
    const __half* Arow = &Hs[wave * 32 + (lane & 31)][(lane >> 5) * 8];
    const half8* B2 = (const half8*)F2;
#pragma unroll
    for (int r = 0; r < R; r++) {
        floatx16 acc2[2];
#pragma unroll
        for (int i = 0; i < 2; i++)
#pragma unroll
            for (int j = 0; j < 16; j++) acc2[i][j] = 0.f;
#pragma unroll
        for (int kbr = 0; kbr < 8; kbr++) {
            half8 a2 = *(const half8*)(Arow + kbr * 16);
#pragma unroll
            for (int nt = 0; nt < 2; nt++) {
                half8 b = B2[(nt * KB + r * 8 + kbr) * 64 + lane];
                acc2[nt] = __builtin_amdgcn_mfma_f32_32x32x16_f16(a2, b, acc2[nt], 0, 0, 0);
            }
        }
        int rbase = m0 + 4 * (lane >> 5);
        __half* Yr = Y2 + (long)r * N * 64;
#pragma unroll
        for (int nt = 0; nt < 2; nt++) {
#pragma unroll
            for (int reg = 0; reg < 16; reg++) {
                int row = rbase + (reg & 3) + 8 * (reg >> 2);
                if (row < N)
                    Yr[(long)row * 64 + nt * 32 + col0] = __float2half_rn(acc2[nt][reg]);
            }
        }
    }
}

// ---- layer-2 gather (R17, reverted to measured-best): QUARTER-WAVE per
// edge (16 lanes x uint2 = 128B row); one uniform predicated 32-edge
// window (8 loads in flight/lane); 2-step shfl reduce; lanes 0-15 store
// float4 (256B out row). ----
__global__ __launch_bounds__(256) void gather_out_kernel(const __half* __restrict__ Y2,
                                                         const float* __restrict__ rs_in,
                                                         const float* __restrict__ rs_out,
                                                         const int* __restrict__ row_ptr,
                                                         const unsigned int* __restrict__ esrc,
                                                         const float* __restrict__ bias,
                                                         float* __restrict__ outp) {
    int n = blockIdx.x * 4 + (threadIdx.x >> 6);
    if (n >= N) return;
    int lane = threadIdx.x & 63;
    int g = lane >> 4;                      // edge sub-slot 0..3
    int cl = lane & 15;                     // 4 cols: c = cl*4
    float4 tot = ((const float4*)bias)[cl];
#pragma unroll
    for (int r = 0; r < R; r++) {
        int key = r * N + n;
        const __half* Yr = Y2 + (long)r * N * 64;
        __half2 a0 = __float2half2_rn(0.f), a1 = a0;
        int beg = row_ptr[key], end = row_ptr[key + 1];
        for (int e = beg; e < end; e += 32) {
            unsigned u[8];
#pragma unroll
            for (int j = 0; j < 8; j++) {
                int idx = e + 4 * j + g;
                u[j] = (idx < end) ? esrc[idx] : 0u;
            }
            uint2 y[8];
#pragma unroll
            for (int j = 0; j < 8; j++)
                y[j] = *(const uint2*)(Yr + (long)(u[j] & 0xffffu) * 64 + cl * 4);
#pragma unroll
            for (int j = 0; j < 8; j++) {
                __half2 cj = __half2half2(__ushort_as_half((unsigned short)(u[j] >> 16)));
                a0 = __hfma2(*(__half2*)&y[j].x, cj, a0);
                a1 = __hfma2(*(__half2*)&y[j].y, cj, a1);
            }
        }
#pragma unroll
        for (int off = 16; off < 64; off <<= 1) {
            unsigned w0 = *(unsigned*)&a0, w1 = *(unsigned*)&a1;
            unsigned v0 = (unsigned)__shfl_xor((int)w0, off, 64);
            unsigned v1 = (unsigned)__shfl_xor((int)w1, off, 64);
            a0 = __hadd2(a0, *(__half2*)&v0);
            a1 = __hadd2(a1, *(__half2*)&v1);
        }
        // self-loop
        uint2 ys = *(const uint2*)(Yr + (long)n * 64 + cl * 4);
        __half2 cs = __float2half2_rn(rs_out[key]);
        a0 = __hfma2(*(__half2*)&ys.x, cs, a0);
        a1 = __hfma2(*(__half2*)&ys.y, cs, a1);
        float2 f0 = __half22float2(a0);
        float2 f1 = __half22float2(a1);
        float ri = rs_in[key];
        tot.x += ri * f0.x;
        tot.y += ri * f0.y;
        tot.z += ri * f1.x;
        tot.w += ri * f1.y;
    }
    if (g == 0) *(float4*)(outp + (long)n * 64 + cl * 4) = tot;
}

extern "C" void kernel_launch(void* const* d_in, const int* in_sizes, int n_in,
                              void* d_out, int out_size, void* d_ws, size_t ws_size,
                              hipStream_t stream) {
    const float* x  = (const float*)d_in[0];
    const int*  src = (const int*)d_in[1];
    const int*  dst = (const int*)d_in[2];
    const float* W1 = (const float*)d_in[3];   // [384][128]
    const float* b1 = (const float*)d_in[4];
    const float* W2 = (const float*)d_in[5];   // [384][64]
    const float* b2 = (const float*)d_in[6];
    float* out = (float*)d_out;
    const int E  = in_sizes[1] / R;
    const int RE = in_sizes[1];
    const int nb = (RE + CHUNK - 1) / CHUNK;      // 1172 edge chunks
    const int L  = 2 * NBKT * nb;                 // ~687k
    const int nb1 = (L + 1023) / 1024;            // ~671 (<=1024)

    char* ws = (char*)d_ws;
    size_t off = 0;
    auto alloc = [&](size_t bytes) -> void* {
        void* p = ws + off;
        off += (bytes + 255) & ~(size_t)255;
        return p;
    };
    float* bsum1    = (float*)alloc(HID * 4);
    float* bsum2    = (float*)alloc(OUT * 4);
    float* rs_in    = (float*)alloc((size_t)M * 4);
    float* rs_out   = (float*)alloc((size_t)M * 4);
    int*   row_ptr  = (int*)alloc((size_t)(M + 1) * 4);
    int*   bh       = (int*)alloc((size_t)L * 4);
    int*   scanv    = (int*)alloc((size_t)L * 4);
    int*   partials = (int*)alloc((size_t)nb1 * 4);
    unsigned* esrc  = (unsigned*)alloc((size_t)RE * 4);
    __half* F1      = (__half*)alloc((size_t)4 * KB * 64 * 8 * 2);
    __half* F2      = (__half*)alloc((size_t)2 * KB * 64 * 8 * 2);
    // region A: ebd(9.6MB)+ebs(4.8MB) during build; Z16 (38.4MB) for layer 1;
    // Y2 (19.2MB) for layer 2 (Z16 dead after mlp's phase 1... Z16 is read
    // by mlp while Y2 is written — keep Y2 SEPARATE from Z16 region).
    char*  regA     = (char*)alloc((size_t)N * 384 * 2);
    int*   ebd      = (int*)regA;
    unsigned short* ebs = (unsigned short*)(regA + (size_t)RE * 4);
    __half* Z16     = (__half*)regA;
    __half* x16     = (__half*)alloc((size_t)N * IN * 2);
    __half* Y2      = (__half*)alloc((size_t)R * N * OUT * 2);   // 19.2MB

    prep_kernel<<<1 + WPK_B + (CVT_N4 + 255) / 256, 256, 0, stream>>>(
        x, W1, W2, b1, b2, (uint2*)x16, F1, F2, bsum1, bsum2);
    p1_kernel<<<nb, 256, 0, stream>>>(src, dst, E, RE, nb, bh);
    scan1_kernel<<<nb1, 1024, 0, stream>>>(bh, scanv, partials, L);
    scan2_kernel<<<1, 1024, 0, stream>>>(partials, nb1);
    p3_kernel<<<nb, 256, 0, stream>>>(src, dst, E, RE, nb, scanv, partials, ebd, ebs);
    pbs_kernel<<<NBKT, BK, 0, stream>>>(scanv, partials, nb, RE, ebs, rs_out);
    pbd_kernel<<<NBKT, BK, 0, stream>>>(scanv, partials, nb, RE, ebd, rs_out,
                                        row_ptr, rs_in, esrc);

    const int ab  = (N + 3) / 4;              // 12500 gather blocks
    const int ggb = (N + 127) / 128;          // 391 MLP blocks

    // layer 1 gather + fused MLP (H in LDS) + layer 2 gather
    gather_kernel<<<ab, 256, 0, stream>>>(x16, rs_in, rs_out, row_ptr, esrc, Z16);
    mfma_mlp_kernel<<<ggb, 256, 0, stream>>>(Z16, F1, F2, bsum1, Y2);
    gather_out_kernel<<<ab, 256, 0, stream>>>(Y2, rs_in, rs_out, row_ptr, esrc,
                                              bsum2, out);
}

// Round 11
// 346.366 us; speedup vs baseline: 1.0246x; 1.0078x over previous
//
#include <hip/hip_runtime.h>
#include <hip/hip_fp16.h>

// RGCN: out = hetero(relu(hetero(x, W1,b1)), W2,b2)
// Layer 1 (IN=HID=128): fused 3-relation gather of x16 -> Z(Nx384).
// MLP FUSED (R21): H = relu(bsum1 + Z@W1) staged in LDS [128][136], then
//   Y2_r = H @ W2_r from LDS A-frags. H16 global round-trip deleted.
// Layer 2 tail: gather_out sums coeff*Y2_r rows + bias -> fp32 out.
// Gather (R17): QUARTER-WAVE per edge (16 lanes x uint4 = 256B row), one
//   uniform predicated 24-edge window, 2-step shfl reduce. ~72us, pinned at
//   the L2/fabric random-line service bound (falsified levers: L2-residency
//   phasing R13/R15, relation-fusion MLP R16, NT R20, eighth-wave R20).
// R18 lesson: zero global atomics. R19: CHUNK 2048 / BK 512 (neutral).
// R22: LAUNCH COMPACTION — prep merged into p1 (block-range split; prep's
//   streaming fills CUs idle during p1's 1172 blocks; one launch fewer).

constexpr int N   = 50000;
constexpr int R   = 3;
constexpr int IN  = 128;
constexpr int HID = 128;
constexpr int OUT = 64;
constexpr int M   = R * N;
constexpr int BK  = 512;
constexpr int NBKT = (M + BK - 1) / BK;    // 293
constexpr int CHUNK = 2048;
constexpr int KB  = 24;                    // 384/16 k-blocks for MFMA
constexpr int CVT_N4 = N * IN / 4;         // 1.6M float4 groups
constexpr int WPK   = 6 * KB * 64;         // 9216 weight frags
constexpr int WPK_B = (WPK + 255) / 256;   // 36 blocks
constexpr int PREP_B = 1 + WPK_B + (CVT_N4 + 255) / 256;   // prep block count

typedef _Float16 half8 __attribute__((ext_vector_type(8)));
typedef float floatx16 __attribute__((ext_vector_type(16)));

// ---- merged prep + P1: blocks [0,nb) = edge-chunk histograms; blocks
// [nb, nb+PREP_B) = bsum / wpack / x fp32->fp16. Independent work, one
// launch, concurrent fill of the machine. ----
__global__ __launch_bounds__(256) void prep_p1_kernel(
        const int* __restrict__ src, const int* __restrict__ dst,
        int E, int RE, int nb, int* __restrict__ bh,
        const float* __restrict__ x,
        const float* __restrict__ W1, const float* __restrict__ W2,
        const float* __restrict__ b1, const float* __restrict__ b2,
        uint2* __restrict__ x16,
        __half* __restrict__ F1, __half* __restrict__ F2,
        float* __restrict__ bsum1, float* __restrict__ bsum2) {
    __shared__ int hd[NBKT], hs[NBKT];
    if (blockIdx.x < (unsigned)nb) {
        // ---- P1 ----
        for (int i = threadIdx.x; i < NBKT; i += 256) { hd[i] = 0; hs[i] = 0; }
        __syncthreads();
        int beg = blockIdx.x * CHUNK, end = min(RE, beg + CHUNK);
        for (int g = beg + (int)threadIdx.x; g < end; g += 256) {
            int rb = ((g >= E) + (g >= 2 * E)) * N;
            atomicAdd(&hd[(rb + dst[g]) >> 9], 1);
            atomicAdd(&hs[(rb + src[g]) >> 9], 1);
        }
        __syncthreads();
        for (int i = threadIdx.x; i < NBKT; i += 256) {
            bh[i * nb + blockIdx.x] = hd[i];
            bh[(NBKT + i) * nb + blockIdx.x] = hs[i];
        }
        return;
    }
    // ---- prep ----
    int b = blockIdx.x - nb;
    if (b == 0) {
        int t = threadIdx.x;
        if (t < HID) bsum1[t] = b1[t] + b1[HID + t] + b1[2 * HID + t];
        if (t < OUT) bsum2[t] = b2[t] + b2[OUT + t] + b2[2 * OUT + t];
        return;
    }
    if (b <= WPK_B) {
        int idx = (b - 1) * 256 + threadIdx.x;
        if (idx < 4 * KB * 64) {
            int nt = idx / (KB * 64), rem = idx % (KB * 64);
            int kb = rem / 64, lane = rem % 64;
            int c = nt * 32 + (lane & 31);
            int k0 = kb * 16 + (lane >> 5) * 8;
            __half h[8];
#pragma unroll
            for (int j = 0; j < 8; j++) h[j] = __float2half_rn(W1[(k0 + j) * 128 + c]);
            *(uint4*)(F1 + (size_t)idx * 8) = *(uint4*)h;
        } else if (idx < 6 * KB * 64) {
            int i2 = idx - 4 * KB * 64;
            int nt = i2 / (KB * 64), rem = i2 % (KB * 64);
            int kb = rem / 64, lane = rem % 64;
            int c = nt * 32 + (lane & 31);
            int k0 = kb * 16 + (lane >> 5) * 8;
            __half h[8];
#pragma unroll
            for (int j = 0; j < 8; j++) h[j] = __float2half_rn(W2[(k0 + j) * 64 + c]);
            *(uint4*)(F2 + (size_t)i2 * 8) = *(uint4*)h;
        }
        return;
    }
    int i = (b - 1 - WPK_B) * 256 + threadIdx.x;
    if (i >= CVT_N4) return;
    float4 v = ((const float4*)x)[i];
    __half2 a = __floats2half2_rn(v.x, v.y);
    __half2 c = __floats2half2_rn(v.z, v.w);
    uint2 o;
    o.x = *(unsigned*)&a;
    o.y = *(unsigned*)&c;
    x16[i] = o;
}

// ---- 2-stage exclusive scan (stage-3 folded into consumers) ----
__global__ void scan1_kernel(const int* __restrict__ in, int* __restrict__ out,
                             int* __restrict__ partials, int L) {
    __shared__ int lds[1024];
    int t = threadIdx.x;
    int idx = blockIdx.x * 1024 + t;
    int v = (idx < L) ? in[idx] : 0;
    lds[t] = v;
    __syncthreads();
    for (int off = 1; off < 1024; off <<= 1) {
        int u = (t >= off) ? lds[t - off] : 0;
        __syncthreads();
        lds[t] += u;
        __syncthreads();
    }
    if (idx < L) out[idx] = lds[t] - v;
    if (t == 1023) partials[blockIdx.x] = lds[1023];
}

// 1024-thread scan over up to 1024 partials (nb1 <= 1024)
__global__ void scan2_kernel(int* __restrict__ partials, int nb1) {
    __shared__ int lds[1024];
    int t = threadIdx.x;
    int v = (t < nb1) ? partials[t] : 0;
    lds[t] = v;
    __syncthreads();
    for (int off = 1; off < 1024; off <<= 1) {
        int u = (t >= off) ? lds[t - off] : 0;
        __syncthreads();
        lds[t] += u;
        __syncthreads();
    }
    if (t < nb1) partials[t] = lds[t] - v;
}

// ---- P3: scatter edges into bucket-sorted buffers via LDS cursors ----
// ebd[pos] = (src<<9)|(dkey&511); ebs[pos] = skey&511 (ushort)
__global__ __launch_bounds__(256) void p3_kernel(const int* __restrict__ src,
                                                 const int* __restrict__ dst,
                                                 int E, int RE, int nb,
                                                 const int* __restrict__ scanv,
                                                 const int* __restrict__ partials,
                                                 int* __restrict__ ebd,
                                                 unsigned short* __restrict__ ebs) {
    __shared__ int cd[NBKT], cs[NBKT];
    for (int i = threadIdx.x; i < NBKT; i += 256) {
        int id = i * nb + blockIdx.x;
        int is = (NBKT + i) * nb + blockIdx.x;
        cd[i] = scanv[id] + partials[id >> 10];
        cs[i] = scanv[is] + partials[is >> 10] - RE;
    }
    __syncthreads();
    int beg = blockIdx.x * CHUNK, end = min(RE, beg + CHUNK);
    for (int g = beg + (int)threadIdx.x; g < end; g += 256) {
        int rb = ((g >= E) + (g >= 2 * E)) * N;
        int s  = src[g];
        int kd = rb + dst[g];
        int pd = atomicAdd(&cd[kd >> 9], 1);
        ebd[pd] = (s << 9) | (kd & 511);
        int ks = rb + s;
        int ps = atomicAdd(&cs[ks >> 9], 1);
        ebs[ps] = (unsigned short)(ks & 511);
    }
}

// ---- PB-S: per s-bucket exact histogram -> rs_out ----
__global__ __launch_bounds__(512) void pbs_kernel(const int* __restrict__ scanv,
                                                  const int* __restrict__ partials,
                                                  int nb, int RE,
                                                  const unsigned short* __restrict__ ebs,
                                                  float* __restrict__ rs_out) {
    __shared__ int cnt[BK];
    int t = threadIdx.x;
    int k = blockIdx.x;
    int i0 = (NBKT + k) * nb;
    int segbeg = scanv[i0] + partials[i0 >> 10] - RE;
    int segend;
    if (k == NBKT - 1) segend = RE;
    else {
        int i1 = i0 + nb;
        segend = scanv[i1] + partials[i1 >> 10] - RE;
    }
    cnt[t] = 0;
    __syncthreads();
    for (int e = segbeg + t; e < segend; e += BK)
        atomicAdd(&cnt[(int)ebs[e]], 1);
    __syncthreads();
    int slot = k * BK + t;
    if (slot < M) rs_out[slot] = rsqrtf((float)(cnt[t] + 1));
}

// ---- PB-D: per d-bucket histogram -> row_ptr/rs_in, scatter coeff-packed esrc ----
__global__ __launch_bounds__(512) void pbd_kernel(const int* __restrict__ scanv,
                                                  const int* __restrict__ partials,
                                                  int nb, int RE,
                                                  const int* __restrict__ ebd,
                                                  const float* __restrict__ rs_out,
                                                  int* __restrict__ row_ptr,
                                                  float* __restrict__ rs_in,
                                                  unsigned int* __restrict__ esrc) {
    __shared__ int cnt[BK];
    __shared__ int cur[BK];
    int t = threadIdx.x;
    int k = blockIdx.x;
    int i0 = k * nb;
    int segbeg = scanv[i0] + partials[i0 >> 10];
    int segend;
    if (k == NBKT - 1) segend = RE;
    else {
        int i1 = (k + 1) * nb;
        segend = scanv[i1] + partials[i1 >> 10];
    }
    cnt[t] = 0;
    __syncthreads();
    for (int e = segbeg + t; e < segend; e += BK)
        atomicAdd(&cnt[ebd[e] & 511], 1);
    __syncthreads();
    int slot = k * BK + t;
    int c = cnt[t];
    cur[t] = c;
    __syncthreads();
    for (int off = 1; off < BK; off <<= 1) {
        int u = (t >= off) ? cur[t - off] : 0;
        __syncthreads();
        cur[t] += u;
        __syncthreads();
    }
    int excl = cur[t] - c;
    if (slot < M) {
        row_ptr[slot] = segbeg + excl;
        rs_in[slot] = rsqrtf((float)(c + 1));   // +1 self-loop
    }
    if (k == NBKT - 1 && t == 0) row_ptr[M] = RE;
    __syncthreads();
    cur[t] = segbeg + excl;
    __syncthreads();
    for (int e = segbeg + t; e < segend; e += BK) {
        int v = ebd[e];
        int key = k * BK + (v & 511);
        int r = (key >= 2 * N) + (key >= N);
        unsigned s = (unsigned)(v >> 9);
        int pos = atomicAdd(&cur[v & 511], 1);
        __half h = __float2half_rn(rs_out[r * N + s]);
        esrc[pos] = s | ((unsigned)__half_as_ushort(h) << 16);
    }
}

// ---- layer-1 gather (R17, unchanged): one wave per node; QUARTER-WAVE
// (16 lanes x uint4 = 256B row) per edge -> 4 edges/instr; one uniform
// predicated 24-edge window (6 loads in flight/lane); pred-out lanes load
// row 0 (L1-hot) with coeff +0; 2-step shfl_xor(16,32) reduce. ----
__global__ __launch_bounds__(256) void gather_kernel(const __half* __restrict__ Xh,
                                                     const float* __restrict__ rs_in,
                                                     const float* __restrict__ rs_out,
                                                     const int* __restrict__ row_ptr,
                                                     const unsigned int* __restrict__ esrc,
                                                     __half* __restrict__ Z16) {
    int n = blockIdx.x * 4 + (threadIdx.x >> 6);
    if (n >= N) return;
    int lane = threadIdx.x & 63;
    int g = lane >> 4;                       // edge sub-slot 0..3
    int cl = lane & 15;                      // 8 cols: c = cl*8
    const __half* xrow = Xh + (long)n * 128 + cl * 8;
    uint4 xn = *(const uint4*)xrow;
#pragma unroll
    for (int r = 0; r < R; r++) {
        int key = r * N + n;
        int beg = row_ptr[key], end = row_ptr[key + 1];
        __half2 a0 = __float2half2_rn(0.f), a1 = a0, a2 = a0, a3 = a0;
        for (int e = beg; e < end; e += 24) {
            unsigned u[6];
#pragma unroll
            for (int j = 0; j < 6; j++) {
                int idx = e + 4 * j + g;
                u[j] = (idx < end) ? esrc[idx] : 0u;   // coeff bits 0 -> adds 0
            }
            uint4 y[6];
#pragma unroll
            for (int j = 0; j < 6; j++)
                y[j] = *(const uint4*)(Xh + (long)(u[j] & 0xffffu) * 128 + cl * 8);
#pragma unroll
            for (int j = 0; j < 6; j++) {
                __half2 cj = __half2half2(__ushort_as_half((unsigned short)(u[j] >> 16)));
                a0 = __hfma2(*(__half2*)&y[j].x, cj, a0);
                a1 = __hfma2(*(__half2*)&y[j].y, cj, a1);
                a2 = __hfma2(*(__half2*)&y[j].z, cj, a2);
                a3 = __hfma2(*(__half2*)&y[j].w, cj, a3);
            }
        }
        // reduce over the 4 edge sub-slots (lanes l, l^16, l^32, l^48)
#pragma unroll
        for (int off = 16; off < 64; off <<= 1) {
            unsigned w0 = *(unsigned*)&a0, w1 = *(unsigned*)&a1;
            unsigned w2 = *(unsigned*)&a2, w3 = *(unsigned*)&a3;
            unsigned v0 = (unsigned)__shfl_xor((int)w0, off, 64);
            unsigned v1 = (unsigned)__shfl_xor((int)w1, off, 64);
            unsigned v2 = (unsigned)__shfl_xor((int)w2, off, 64);
            unsigned v3 = (unsigned)__shfl_xor((int)w3, off, 64);
            a0 = __hadd2(a0, *(__half2*)&v0);
            a1 = __hadd2(a1, *(__half2*)&v1);
            a2 = __hadd2(a2, *(__half2*)&v2);
            a3 = __hadd2(a3, *(__half2*)&v3);
        }
        __half2 cs = __float2half2_rn(rs_out[key]);
        a0 = __hfma2(*(__half2*)&xn.x, cs, a0);
        a1 = __hfma2(*(__half2*)&xn.y, cs, a1);
        a2 = __hfma2(*(__half2*)&xn.z, cs, a2);
        a3 = __hfma2(*(__half2*)&xn.w, cs, a3);
        __half2 ri = __float2half2_rn(rs_in[key]);
        a0 = __hmul2(a0, ri);
        a1 = __hmul2(a1, ri);
        a2 = __hmul2(a2, ri);
        a3 = __hmul2(a3, ri);
        if (g == 0) {
            uint4 o;
            o.x = *(unsigned*)&a0;
            o.y = *(unsigned*)&a1;
            o.z = *(unsigned*)&a2;
            o.w = *(unsigned*)&a3;
            *(uint4*)(Z16 + (long)n * 384 + r * 128 + cl * 8) = o;
        }
    }
}

// ---- fused MLP (R21): H = relu(bsum1 + Z16@W1) staged in LDS, then
// Y2_r = H @ W2_r for r=0..2. 4 waves x 32-row strips; LDS [128][136].
// C/D map: col=lane&31, row=(reg&3)+8*(reg>>2)+4*(lane>>5)  [m74/m101]
// A-frag map: row=lane&31, k=(lane>>5)*8+j. ----
__global__ __launch_bounds__(256) void mfma_mlp_kernel(const __half* __restrict__ Z16,
                                                       const __half* __restrict__ F1,
                                                       const __half* __restrict__ F2,
                                                       const float* __restrict__ bias,
                                                       __half* __restrict__ Y2) {
    __shared__ __half Hs[128][136];
    int wave = threadIdx.x >> 6, lane = threadIdx.x & 63;
    int m0 = blockIdx.x * 128 + wave * 32;
    int mr = min(m0 + (lane & 31), N - 1);
    const half8* A = (const half8*)(Z16 + (long)mr * 384 + (lane >> 5) * 8);
    const half8* B1 = (const half8*)F1;
    floatx16 acc[4];
#pragma unroll
    for (int i = 0; i < 4; i++)
#pragma unroll
        for (int j = 0; j < 16; j++) acc[i][j] = 0.f;

    half8 a = A[0];
    for (int kb = 0; kb < KB; kb++) {
        half8 an = (kb < KB - 1) ? A[(kb + 1) * 2] : a;
#pragma unroll
        for (int nt = 0; nt < 4; nt++) {
            half8 b = B1[(nt * KB + kb) * 64 + lane];
            acc[nt] = __builtin_amdgcn_mfma_f32_32x32x16_f16(a, b, acc[nt], 0, 0, 0);
        }
        a = an;
    }
    float bv[4];
#pragma unroll
    for (int nt = 0; nt < 4; nt++) bv[nt] = bias[nt * 32 + (lane & 31)];
    int lrbase = wave * 32 + 4 * (lane >> 5);
    int col0 = lane & 31;
#pragma unroll
    for (int nt = 0; nt < 4; nt++) {
#pragma unroll
        for (int reg = 0; reg < 16; reg++) {
            int lrow = lrbase + (reg & 3) + 8 * (reg >> 2);
            Hs[lrow][nt * 32 + col0] =
                __float2half_rn(fmaxf(acc[nt][reg] + bv[nt], 0.f));
        }
    }
    __syncthreads();

    // phase 2: Y2_r = H @ W2_r. A-frags from own strip in LDS.
    const __half* Arow = &Hs[wave * 32 + (lane & 31)][(lane >> 5) * 8];
    const half8* B2 = (const half8*)F2;
#pragma unroll
    for (int r = 0; r < R; r++) {
        floatx16 acc2[2];
#pragma unroll
        for (int i = 0; i < 2; i++)
#pragma unroll
            for (int j = 0; j < 16; j++) acc2[i][j] = 0.f;
#pragma unroll
        for (int kbr = 0; kbr < 8; kbr++) {
            half8 a2 = *(const half8*)(Arow + kbr * 16);
#pragma unroll
            for (int nt = 0; nt < 2; nt++) {
                half8 b = B2[(nt * KB + r * 8 + kbr) * 64 + lane];
                acc2[nt] = __builtin_amdgcn_mfma_f32_32x32x16_f16(a2, b, acc2[nt], 0, 0, 0);
            }
        }
        int rbase = m0 + 4 * (lane >> 5);
        __half* Yr = Y2 + (long)r * N * 64;
#pragma unroll
        for (int nt = 0; nt < 2; nt++) {
#pragma unroll
            for (int reg = 0; reg < 16; reg++) {
                int row = rbase + (reg & 3) + 8 * (reg >> 2);
                if (row < N)
                    Yr[(long)row * 64 + nt * 32 + col0] = __float2half_rn(acc2[nt][reg]);
            }
        }
    }
}

// ---- layer-2 gather (R17): QUARTER-WAVE per edge (16 lanes x uint2 =
// 128B row); one uniform predicated 32-edge window (8 loads in
// flight/lane); 2-step shfl reduce; lanes 0-15 store float4. ----
__global__ __launch_bounds__(256) void gather_out_kernel(const __half* __restrict__ Y2,
                                                         const float* __restrict__ rs_in,
                                                         const float* __restrict__ rs_out,
                                                         const int* __restrict__ row_ptr,
                                                         const unsigned int* __restrict__ esrc,
                                                         const float* __restrict__ bias,
                                                         float* __restrict__ outp) {
    int n = blockIdx.x * 4 + (threadIdx.x >> 6);
    if (n >= N) return;
    int lane = threadIdx.x & 63;
    int g = lane >> 4;                      // edge sub-slot 0..3
    int cl = lane & 15;                     // 4 cols: c = cl*4
    float4 tot = ((const float4*)bias)[cl];
#pragma unroll
    for (int r = 0; r < R; r++) {
        int key = r * N + n;
        const __half* Yr = Y2 + (long)r * N * 64;
        __half2 a0 = __float2half2_rn(0.f), a1 = a0;
        int beg = row_ptr[key], end = row_ptr[key + 1];
        for (int e = beg; e < end; e += 32) {
            unsigned u[8];
#pragma unroll
            for (int j = 0; j < 8; j++) {
                int idx = e + 4 * j + g;
                u[j] = (idx < end) ? esrc[idx] : 0u;
            }
            uint2 y[8];
#pragma unroll
            for (int j = 0; j < 8; j++)
                y[j] = *(const uint2*)(Yr + (long)(u[j] & 0xffffu) * 64 + cl * 4);
#pragma unroll
            for (int j = 0; j < 8; j++) {
                __half2 cj = __half2half2(__ushort_as_half((unsigned short)(u[j] >> 16)));
                a0 = __hfma2(*(__half2*)&y[j].x, cj, a0);
                a1 = __hfma2(*(__half2*)&y[j].y, cj, a1);
            }
        }
#pragma unroll
        for (int off = 16; off < 64; off <<= 1) {
            unsigned w0 = *(unsigned*)&a0, w1 = *(unsigned*)&a1;
            unsigned v0 = (unsigned)__shfl_xor((int)w0, off, 64);
            unsigned v1 = (unsigned)__shfl_xor((int)w1, off, 64);
            a0 = __hadd2(a0, *(__half2*)&v0);
            a1 = __hadd2(a1, *(__half2*)&v1);
        }
        // self-loop
        uint2 ys = *(const uint2*)(Yr + (long)n * 64 + cl * 4);
        __half2 cs = __float2half2_rn(rs_out[key]);
        a0 = __hfma2(*(__half2*)&ys.x, cs, a0);
        a1 = __hfma2(*(__half2*)&ys.y, cs, a1);
        float2 f0 = __half22float2(a0);
        float2 f1 = __half22float2(a1);
        float ri = rs_in[key];
        tot.x += ri * f0.x;
        tot.y += ri * f0.y;
        tot.z += ri * f1.x;
        tot.w += ri * f1.y;
    }
    if (g == 0) *(float4*)(outp + (long)n * 64 + cl * 4) = tot;
}

extern "C" void kernel_launch(void* const* d_in, const int* in_sizes, int n_in,
                              void* d_out, int out_size, void* d_ws, size_t ws_size,
                              hipStream_t stream) {
    const float* x  = (const float*)d_in[0];
    const int*  src = (const int*)d_in[1];
    const int*  dst = (const int*)d_in[2];
    const float* W1 = (const float*)d_in[3];   // [384][128]
    const float* b1 = (const float*)d_in[4];
    const float* W2 = (const float*)d_in[5];   // [384][64]
    const float* b2 = (const float*)d_in[6];
    float* out = (float*)d_out;
    const int E  = in_sizes[1] / R;
    const int RE = in_sizes[1];
    const int nb = (RE + CHUNK - 1) / CHUNK;      // 1172 edge chunks
    const int L  = 2 * NBKT * nb;                 // ~687k
    const int nb1 = (L + 1023) / 1024;            // ~671 (<=1024)

    char* ws = (char*)d_ws;
    size_t off = 0;
    auto alloc = [&](size_t bytes) -> void* {
        void* p = ws + off;
        off += (bytes + 255) & ~(size_t)255;
        return p;
    };
    float* bsum1    = (float*)alloc(HID * 4);
    float* bsum2    = (float*)alloc(OUT * 4);
    float* rs_in    = (float*)alloc((size_t)M * 4);
    float* rs_out   = (float*)alloc((size_t)M * 4);
    int*   row_ptr  = (int*)alloc((size_t)(M + 1) * 4);
    int*   bh       = (int*)alloc((size_t)L * 4);
    int*   scanv    = (int*)alloc((size_t)L * 4);
    int*   partials = (int*)alloc((size_t)nb1 * 4);
    unsigned* esrc  = (unsigned*)alloc((size_t)RE * 4);
    __half* F1      = (__half*)alloc((size_t)4 * KB * 64 * 8 * 2);
    __half* F2      = (__half*)alloc((size_t)2 * KB * 64 * 8 * 2);
    // region A: ebd(9.6MB)+ebs(4.8MB) during build; Z16 (38.4MB) for layer 1.
    // Y2 kept SEPARATE (mlp reads Z16 while writing Y2).
    char*  regA     = (char*)alloc((size_t)N * 384 * 2);
    int*   ebd      = (int*)regA;
    unsigned short* ebs = (unsigned short*)(regA + (size_t)RE * 4);
    __half* Z16     = (__half*)regA;
    __half* x16     = (__half*)alloc((size_t)N * IN * 2);
    __half* Y2      = (__half*)alloc((size_t)R * N * OUT * 2);   // 19.2MB

    prep_p1_kernel<<<nb + PREP_B, 256, 0, stream>>>(
        src, dst, E, RE, nb, bh, x, W1, W2, b1, b2, (uint2*)x16, F1, F2,
        bsum1, bsum2);
    scan1_kernel<<<nb1, 1024, 0, stream>>>(bh, scanv, partials, L);
    scan2_kernel<<<1, 1024, 0, stream>>>(partials, nb1);
    p3_kernel<<<nb, 256, 0, stream>>>(src, dst, E, RE, nb, scanv, partials, ebd, ebs);
    pbs_kernel<<<NBKT, BK, 0, stream>>>(scanv, partials, nb, RE, ebs, rs_out);
    pbd_kernel<<<NBKT, BK, 0, stream>>>(scanv, partials, nb, RE, ebd, rs_out,
                                        row_ptr, rs_in, esrc);

    const int ab  = (N + 3) / 4;              // 12500 gather blocks
    const int ggb = (N + 127) / 128;          // 391 MLP blocks

    // layer 1 gather + fused MLP (H in LDS) + layer 2 gather
    gather_kernel<<<ab, 256, 0, stream>>>(x16, rs_in, rs_out, row_ptr, esrc, Z16);
    mfma_mlp_kernel<<<ggb, 256, 0, stream>>>(Z16, F1, F2, bsum1, Y2);
    gather_out_kernel<<<ab, 256, 0, stream>>>(Y2, rs_in, rs_out, row_ptr, esrc,
                                              bsum2, out);
}